// Round 15
// baseline (410.420 us; speedup 1.0000x reference)
//
#include <hip/hip_runtime.h>
#include <cmath>

typedef __attribute__((ext_vector_type(8))) short short8;
typedef __attribute__((ext_vector_type(4))) short shortx4;
typedef __attribute__((ext_vector_type(4))) float floatx4;
typedef __attribute__((ext_vector_type(2))) float floatx2;
typedef __attribute__((ext_vector_type(4))) int intx4;

#define N_G 50000
#define E_G 800000
#define N_S 10000
#define E_S 160000
#define NT (N_G + N_S)      // 60000 combined nodes
#define ET (E_G + E_S)      // 960000 combined edges
#define BATCH 8
#define STRIDE 64           // fixed CSR stride (deg ~ Poisson(16); P(>64) ~ 1e-18)
#define FPASS 8             // fill: XCD-aligned dst groups

__device__ __forceinline__ float b2f(short s) {
    unsigned u = ((unsigned)(unsigned short)s) << 16;
    return __builtin_bit_cast(float, u);
}
__device__ __forceinline__ short f2b(float f) {
    unsigned u = __builtin_bit_cast(unsigned, f);
    u += 0x7FFF + ((u >> 16) & 1);   // RNE
    return (short)(u >> 16);
}

// ---------------- init: zeros + bounds + X0 bf16/fp8 + weight repack (merged) ------
struct RepArgs { const float* Wr[6]; const float* Wn[6]; short* dst[6]; int cin[6]; int nk[6]; int groups[6]; };
__global__ void init_kernel(const float* __restrict__ gx, const float* __restrict__ sx,
                            short* __restrict__ X0, unsigned char* __restrict__ X0_8,
                            int* __restrict__ dcount, float* __restrict__ pooled,
                            const int* __restrict__ g_batch, const int* __restrict__ s_batch,
                            int* __restrict__ starts, RepArgs ra, int total_groups) {
    int t = blockIdx.x * blockDim.x + threadIdx.x;
    if (t < NT * 16) {
        size_t e = (size_t)t * 4;
        const float* src = (e < (size_t)N_G * 64) ? (gx + e) : (sx + (e - (size_t)N_G * 64));
        floatx4 v = *(const floatx4*)src;
        shortx4 o;
        o[0] = f2b(v[0]); o[1] = f2b(v[1]); o[2] = f2b(v[2]); o[3] = f2b(v[3]);
        *(shortx4*)(X0 + e) = o;
        int w8 = 0;
        w8 = __builtin_amdgcn_cvt_pk_fp8_f32(v[0], v[1], w8, false);
        w8 = __builtin_amdgcn_cvt_pk_fp8_f32(v[2], v[3], w8, true);
        *(unsigned int*)(X0_8 + e) = (unsigned int)w8;
    }
    if (t < NT) dcount[t] = 0;
    if (t < 16 * 192) pooled[t] = 0.f;
    if (t <= 16) {
        int b = t;
        if (b == 16) { starts[16] = NT; }
        else {
            int key, n, base;
            const int* arr;
            if (b < 8) { arr = g_batch; n = N_G; key = b; base = 0; }
            else       { arr = s_batch; n = N_S; key = b - 8; base = N_G; }
            int lo = 0, hi = n;
            while (lo < hi) { int mid = (lo + hi) >> 1; if (arr[mid] < key) lo = mid + 1; else hi = mid; }
            starts[b] = base + lo;
        }
    }
    // weight repack: fp32 [o][c] -> bf16 MFMA-fragment order
    if (t < total_groups) {
        int seg = 0, off = t;
        while (seg < 5 && off >= ra.groups[seg]) { off -= ra.groups[seg]; ++seg; }
        int CIN = ra.cin[seg], NK = ra.nk[seg];
        int lane = off & 63;
        int rest = off >> 6;
        int tt = rest % NK;
        int ot = rest / NK;
        int o = ot * 16 + (lane & 15);
        int kk = tt * 32 + (lane >> 4) * 8;
        const float* src = (kk < CIN) ? (ra.Wr[seg] + (size_t)o * CIN + kk)
                                      : (ra.Wn[seg] + (size_t)o * CIN + (kk - CIN));
        floatx4 u0 = *(const floatx4*)src;
        floatx4 u1 = *(const floatx4*)(src + 4);
        short8 d;
        d[0]=f2b(u0[0]); d[1]=f2b(u0[1]); d[2]=f2b(u0[2]); d[3]=f2b(u0[3]);
        d[4]=f2b(u1[0]); d[5]=f2b(u1[1]); d[6]=f2b(u1[2]); d[7]=f2b(u1[3]);
        *(short8*)(ra.dst[seg] + (size_t)off * 8) = d;
    }
}

// ---------------- stride-CSR fill: XCD-aligned dst groups ----------------
__global__ void fill_kernel(const int* __restrict__ g_ei, const int* __restrict__ s_ei,
                            int* __restrict__ dcount, int* __restrict__ csr) {
    int pass = blockIdx.x & (FPASS - 1);
    int lb   = blockIdx.x >> 3;
    int t = lb * blockDim.x + threadIdx.x;
    if (t >= ET) return;
    int dst;
    if (t < E_G) dst = g_ei[E_G + t];
    else         dst = s_ei[E_S + (t - E_G)] + N_G;
    int lo = pass * (NT / FPASS);
    int hi = lo + (NT / FPASS);
    if (dst < lo || dst >= hi) return;
    int src;
    if (t < E_G) src = g_ei[t];
    else         src = s_ei[t - E_G] + N_G;
    int slot = atomicAdd(&dcount[dst], 1);
    if (slot < STRIDE) csr[(size_t)dst * STRIDE + slot] = src;
}

// ---------------- fp8 gather aggregation (all layers) -------------
template<int C>
__global__ void agg8_kernel(const unsigned char* __restrict__ x8, const int* __restrict__ dcount,
                            const int* __restrict__ csr, short* __restrict__ out) {
    constexpr int C16 = C / 16;
    int t = blockIdx.x * blockDim.x + threadIdx.x;
    if (t >= NT * C16) return;
    int node = t / C16;
    int ch   = t % C16;
    int e0 = node * STRIDE;
    int e1 = e0 + min(dcount[node], STRIDE);
    float acc[16];
    #pragma unroll
    for (int j = 0; j < 16; ++j) acc[j] = 0.f;
    for (int e = e0; e < e1; ++e) {
        int s = csr[e];
        intx4 w = *(const intx4*)(x8 + (size_t)s * C + ch * 16);
        #pragma unroll
        for (int q = 0; q < 4; ++q) {
            floatx2 f0 = __builtin_amdgcn_cvt_pk_f32_fp8(w[q], false);
            floatx2 f1 = __builtin_amdgcn_cvt_pk_f32_fp8(w[q], true);
            acc[q * 4 + 0] += f0[0];
            acc[q * 4 + 1] += f0[1];
            acc[q * 4 + 2] += f1[0];
            acc[q * 4 + 3] += f1[1];
        }
    }
    short8 o0, o1;
    #pragma unroll
    for (int j = 0; j < 8; ++j) { o0[j] = f2b(acc[j]); o1[j] = f2b(acc[8 + j]); }
    short8* q = (short8*)(out + (size_t)node * C + ch * 16);
    q[0] = o0; q[1] = o1;
}

// ---------------- LDS-staged dual-GEMM + bias + ELU (+ optional fused pooling) ----
// blockIdx.z: 0=g branch, 1=s branch (block-uniform weight staging).
// blockIdx.y: o-slice of OTN 16-wide tiles, staged to LDS (<=64KB).
// Each of 4 waves processes RPW row-tiles, reusing each B fragment RPW times.
template<int CIN, int COUT, int OTN, int RPW, bool POOL>
__global__ __launch_bounds__(256, 1) void gemm_lds_kernel(
        const short* __restrict__ A1, const short* __restrict__ A2,
        const short* __restrict__ gWF, const short* __restrict__ sWF,
        const float* __restrict__ gB, const float* __restrict__ sB,
        short* __restrict__ out, unsigned char* __restrict__ out8,
        float* __restrict__ pooled, const int* __restrict__ starts) {
    constexpr int NK = CIN / 16;
    __shared__ short lds[OTN * NK * 512];   // OTN*NK KB (<= 64KB)
    int z = blockIdx.z;
    const short* WF = z ? sWF : gWF;
    const float* bias = z ? sB : gB;
    int rowBase  = z ? N_G : 0;
    int rowTiles = z ? (N_S / 16) : (N_G / 16);   // 625 : 3125
    int rtBase = blockIdx.x * (4 * RPW);
    if (rtBase >= rowTiles) return;               // block-uniform: safe before barrier
    // stage this o-slice's B fragments into LDS
    const short* wsrc = WF + ((size_t)(blockIdx.y * OTN) * NK) * 512;
    for (int i = threadIdx.x; i < OTN * NK * 64; i += 256)
        *(short8*)(lds + (size_t)i * 8) = *(const short8*)(wsrc + (size_t)i * 8);
    __syncthreads();
    int wv = threadIdx.x >> 6, lane = threadIdx.x & 63;
    int id = lane & 15, quad = lane >> 4;
    int rt[RPW]; bool act[RPW];
    short8 a[RPW][NK];
    #pragma unroll
    for (int r = 0; r < RPW; ++r) {
        rt[r] = rtBase + wv * RPW + r;
        act[r] = rt[r] < rowTiles;
        int arow = rowBase + (act[r] ? rt[r] : 0) * 16 + id;
        #pragma unroll
        for (int t = 0; t < NK; ++t) {
            int kk = t * 32 + quad * 8;
            const short* p = (kk < CIN) ? (A1 + (size_t)arow * CIN + kk)
                                        : (A2 + (size_t)arow * CIN + (kk - CIN));
            a[r][t] = *(const short8*)p;
        }
    }
    int seg0[RPW], seg1[RPW];
    if (POOL) {
        #pragma unroll
        for (int r = 0; r < RPW; ++r) {
            int r0 = rowBase + (act[r] ? rt[r] : 0) * 16;
            int s0 = 0;
            while (s0 < 15 && starts[s0 + 1] <= r0) ++s0;
            int s1 = s0;
            while (s1 < 15 && starts[s1 + 1] <= r0 + 15) ++s1;
            seg0[r] = s0; seg1[r] = s1;
        }
    }
    for (int oi = 0; oi < OTN; ++oi) {
        short8 b[NK];
        #pragma unroll
        for (int t = 0; t < NK; ++t)
            b[t] = *(const short8*)(lds + (((size_t)(oi * NK + t)) * 64 + lane) * 8);
        int o = (blockIdx.y * OTN + oi) * 16 + id;
        float bv = bias[o];
        #pragma unroll
        for (int r = 0; r < RPW; ++r) {
            if (!act[r]) continue;               // wave-uniform predicate
            floatx4 acc = {0.f, 0.f, 0.f, 0.f};
            #pragma unroll
            for (int t = 0; t < NK; ++t)
                acc = __builtin_amdgcn_mfma_f32_16x16x32_bf16(a[r][t], b[t], acc, 0, 0, 0);
            float vr[4];
            #pragma unroll
            for (int q = 0; q < 4; ++q) {
                float v = acc[q] + bv;
                vr[q] = (v > 0.f) ? v : (expf(v) - 1.f);
            }
            int r0 = rowBase + rt[r] * 16;
            if (!POOL) {
                #pragma unroll
                for (int q = 0; q < 4; ++q) {
                    int nrow = r0 + quad * 4 + q;   // C/D: col=lane&15, row=quad*4+reg
                    out[(size_t)nrow * COUT + o] = f2b(vr[q]);
                    if (out8) {
                        int w8 = __builtin_amdgcn_cvt_pk_fp8_f32(vr[q], vr[q], 0, false);
                        out8[(size_t)nrow * COUT + o] = (unsigned char)(w8 & 0xFF);
                    }
                }
            } else if (seg0[r] == seg1[r]) {
                float vsum = vr[0] + vr[1] + vr[2] + vr[3];
                vsum += __shfl_down(vsum, 32, 64);
                vsum += __shfl_down(vsum, 16, 64);
                if (lane < 16) atomicAdd(&pooled[seg0[r] * 192 + o], vsum);
            } else {
                #pragma unroll
                for (int q = 0; q < 4; ++q) {
                    int nrow = r0 + quad * 4 + q;
                    int sg = seg0[r];
                    while (sg < seg1[r] && starts[sg + 1] <= nrow) ++sg;
                    atomicAdd(&pooled[sg * 192 + o], vr[q]);
                }
            }
        }
    }
}

// ---------------- build MLP input [8,448] ----------------
__global__ void build_in_kernel(const float* __restrict__ pooled, const int* __restrict__ starts,
                                const float* __restrict__ point, float* __restrict__ mlp_in) {
    int t = blockIdx.x * blockDim.x + threadIdx.x;
    if (t >= BATCH * 448) return;
    int b = t / 448, j = t % 448;
    float v;
    if (j < 192) {
        int c = starts[b + 1] - starts[b];
        v = pooled[b * 192 + j] / (float)max(c, 1);
    } else if (j < 384) {
        int c = starts[9 + b] - starts[8 + b];
        v = pooled[(8 + b) * 192 + (j - 192)] / (float)max(c, 1);
    } else {
        v = point[b * 64 + (j - 384)];
    }
    mlp_in[t] = v;
}

// ---------------- dense layer: one wave per output neuron ----------------
__global__ __launch_bounds__(256) void dense_wave_kernel(
        const float* __restrict__ in, const float* __restrict__ W,
        const float* __restrict__ bias, float* __restrict__ out,
        int I, int O, int relu) {
    int wave = (blockIdx.x * blockDim.x + threadIdx.x) >> 6;
    int lane = threadIdx.x & 63;
    if (wave >= BATCH * O) return;
    int b = wave / O, o = wave % O;
    const float* x = in + (size_t)b * I;
    const float* w = W + (size_t)o * I;
    float acc = 0.f;
    for (int i = lane; i < I; i += 64) acc += x[i] * w[i];
    #pragma unroll
    for (int off = 32; off > 0; off >>= 1) acc += __shfl_down(acc, off, 64);
    if (lane == 0) {
        acc += bias[o];
        if (relu) acc = fmaxf(acc, 0.f);
        out[wave] = acc;
    }
}

extern "C" void kernel_launch(void* const* d_in, const int* in_sizes, int n_in,
                              void* d_out, int out_size, void* d_ws, size_t ws_size,
                              hipStream_t stream) {
    const float* graph_x = (const float*)d_in[0];
    const float* sub_x   = (const float*)d_in[1];
    const float* point   = (const float*)d_in[2];
    const int*   g_ei    = (const int*)d_in[3];
    const int*   g_batch = (const int*)d_in[4];
    const int*   s_ei    = (const int*)d_in[5];
    const int*   s_batch = (const int*)d_in[6];
    const float* gB1=(const float*)d_in[9],  *gB2=(const float*)d_in[12], *gB3=(const float*)d_in[15];
    const float* sB1=(const float*)d_in[18], *sB2=(const float*)d_in[21], *sB3=(const float*)d_in[24];
    const float* l1W=(const float*)d_in[25], *l1b=(const float*)d_in[26];
    const float* l2W=(const float*)d_in[27], *l2b=(const float*)d_in[28];
    const float* l3W=(const float*)d_in[29], *l3b=(const float*)d_in[30];

    char* ws = (char*)d_ws;
    size_t off = 0;
    auto alloc = [&](size_t bytes) -> char* {
        char* p = ws + off;
        off = (off + bytes + 255) & ~(size_t)255;
        return p;
    };
    int* dcount = (int*)alloc((size_t)NT * 4);
    int* csr = (int*)alloc((size_t)NT * STRIDE * 4);   // 15.36 MB stride-CSR

    // fragment-ordered bf16 weight slab: per layer COUT*2*CIN elems
    const int fsz[3] = {128 * 2 * 64, 256 * 2 * 128, 192 * 2 * 256};
    short* wfrag = (short*)alloc((size_t)(fsz[0] + fsz[1] + fsz[2]) * 2 * 2);
    short* gWF[3], *sWF[3];
    { size_t o2 = 0;
      for (int l = 0; l < 3; ++l) { gWF[l] = wfrag + o2; o2 += fsz[l]; }
      for (int l = 0; l < 3; ++l) { sWF[l] = wfrag + o2; o2 += fsz[l]; } }

    short* X0  = (short*)alloc((size_t)NT * 64 * 2);
    unsigned char* X0_8 = (unsigned char*)alloc((size_t)NT * 64);
    short* agg = (short*)alloc((size_t)NT * 256 * 2);
    short* h1  = (short*)alloc((size_t)NT * 128 * 2);
    short* h2  = (short*)alloc((size_t)NT * 256 * 2);
    unsigned char* h1_8 = (unsigned char*)alloc((size_t)NT * 128);
    unsigned char* h2_8 = (unsigned char*)alloc((size_t)NT * 256);

    float* pooled = (float*)alloc(16 * 192 * 4);
    int* starts = (int*)alloc(17 * 4);
    float* mlp_in = (float*)alloc(BATCH * 448 * 4);
    float* mlp_h1 = (float*)alloc(BATCH * 600 * 4);
    float* mlp_h2 = (float*)alloc(BATCH * 256 * 4);

    // weight repack args (merged into init)
    RepArgs ra;
    const int cin_l[3] = {64, 128, 256};
    const int nk_l[3]  = {4, 8, 16};
    const int not_l[3] = {8, 16, 12};
    const int wr_idx[6] = {7, 10, 13, 16, 19, 22};
    int total_groups = 0;
    for (int s = 0; s < 6; ++s) {
        int l = s % 3;
        ra.Wr[s] = (const float*)d_in[wr_idx[s]];
        ra.Wn[s] = (const float*)d_in[wr_idx[s] + 1];
        ra.dst[s] = (s < 3) ? gWF[l] : sWF[l];
        ra.cin[s] = cin_l[l];
        ra.nk[s] = nk_l[l];
        ra.groups[s] = not_l[l] * nk_l[l] * 64;
        total_groups += ra.groups[s];
    }

    init_kernel<<<(NT * 16 + 255) / 256, 256, 0, stream>>>(graph_x, sub_x, X0, X0_8, dcount,
                                                           pooled, g_batch, s_batch, starts,
                                                           ra, total_groups);

    fill_kernel<<<((ET + 255) / 256) * FPASS, 256, 0, stream>>>(g_ei, s_ei, dcount, csr);

    // gemm grids: x covers g-branch row tiles (3125) at 8 tiles/block; s-branch
    // (625 tiles) exits early beyond block 78. y = o-slices, z = branch.
    const int gx = (3125 + 7) / 8;   // 391

    agg8_kernel<64><<<(NT * 4 + 255) / 256, 256, 0, stream>>>(X0_8, dcount, csr, agg);
    gemm_lds_kernel<64, 128, 8, 2, false><<<dim3(gx, 1, 2), 256, 0, stream>>>(
        agg, X0, gWF[0], sWF[0], gB1, sB1, h1, h1_8, nullptr, nullptr);
    agg8_kernel<128><<<(NT * 8 + 255) / 256, 256, 0, stream>>>(h1_8, dcount, csr, agg);
    gemm_lds_kernel<128, 256, 8, 2, false><<<dim3(gx, 2, 2), 256, 0, stream>>>(
        agg, h1, gWF[1], sWF[1], gB2, sB2, h2, h2_8, nullptr, nullptr);
    agg8_kernel<256><<<(NT * 16 + 255) / 256, 256, 0, stream>>>(h2_8, dcount, csr, agg);
    gemm_lds_kernel<256, 192, 4, 2, true><<<dim3(gx, 3, 2), 256, 0, stream>>>(
        agg, h2, gWF[2], sWF[2], gB3, sB3, nullptr, nullptr, pooled, starts);

    build_in_kernel<<<(BATCH * 448 + 255) / 256, 256, 0, stream>>>(pooled, starts, point, mlp_in);
    dense_wave_kernel<<<(BATCH * 600 + 3) / 4, 256, 0, stream>>>(mlp_in, l1W, l1b, mlp_h1, 448, 600, 1);
    dense_wave_kernel<<<(BATCH * 256 + 3) / 4, 256, 0, stream>>>(mlp_h1, l2W, l2b, mlp_h2, 600, 256, 1);
    dense_wave_kernel<<<(BATCH * 64 + 3) / 4, 256, 0, stream>>>(mlp_h2, l3W, l3b, (float*)d_out, 256, 64, 0);
}

// Round 17
// 395.347 us; speedup vs baseline: 1.0381x; 1.0381x over previous
//
#include <hip/hip_runtime.h>
#include <cmath>

typedef __attribute__((ext_vector_type(8))) short short8;
typedef __attribute__((ext_vector_type(4))) short shortx4;
typedef __attribute__((ext_vector_type(4))) float floatx4;
typedef __attribute__((ext_vector_type(2))) float floatx2;
typedef __attribute__((ext_vector_type(4))) int intx4;

#define N_G 50000
#define E_G 800000
#define N_S 10000
#define E_S 160000
#define NT (N_G + N_S)      // 60000 combined nodes
#define ET (E_G + E_S)      // 960000 combined edges
#define BATCH 8
#define STRIDE 64           // fixed CSR stride (deg ~ Poisson(16); P(>64) ~ 1e-18)
#define FPASS 8             // fill: XCD-aligned dst groups

__device__ __forceinline__ float b2f(short s) {
    unsigned u = ((unsigned)(unsigned short)s) << 16;
    return __builtin_bit_cast(float, u);
}
__device__ __forceinline__ short f2b(float f) {
    unsigned u = __builtin_bit_cast(unsigned, f);
    u += 0x7FFF + ((u >> 16) & 1);   // RNE
    return (short)(u >> 16);
}

// ---------------- init: zeros + bounds + X0 bf16/fp8 + weight repack (merged) ------
struct RepArgs { const float* Wr[6]; const float* Wn[6]; short* dst[6]; int cin[6]; int nk[6]; int groups[6]; };
__global__ void init_kernel(const float* __restrict__ gx, const float* __restrict__ sx,
                            short* __restrict__ X0, unsigned char* __restrict__ X0_8,
                            int* __restrict__ dcount, float* __restrict__ pooled,
                            const int* __restrict__ g_batch, const int* __restrict__ s_batch,
                            int* __restrict__ starts, RepArgs ra, int total_groups) {
    int t = blockIdx.x * blockDim.x + threadIdx.x;
    if (t < NT * 16) {
        size_t e = (size_t)t * 4;
        const float* src = (e < (size_t)N_G * 64) ? (gx + e) : (sx + (e - (size_t)N_G * 64));
        floatx4 v = *(const floatx4*)src;
        shortx4 o;
        o[0] = f2b(v[0]); o[1] = f2b(v[1]); o[2] = f2b(v[2]); o[3] = f2b(v[3]);
        *(shortx4*)(X0 + e) = o;
        int w8 = 0;
        w8 = __builtin_amdgcn_cvt_pk_fp8_f32(v[0], v[1], w8, false);
        w8 = __builtin_amdgcn_cvt_pk_fp8_f32(v[2], v[3], w8, true);
        *(unsigned int*)(X0_8 + e) = (unsigned int)w8;
    }
    if (t < NT) dcount[t] = 0;
    if (t < 16 * 192) pooled[t] = 0.f;
    if (t <= 16) {
        int b = t;
        if (b == 16) { starts[16] = NT; }
        else {
            int key, n, base;
            const int* arr;
            if (b < 8) { arr = g_batch; n = N_G; key = b; base = 0; }
            else       { arr = s_batch; n = N_S; key = b - 8; base = N_G; }
            int lo = 0, hi = n;
            while (lo < hi) { int mid = (lo + hi) >> 1; if (arr[mid] < key) lo = mid + 1; else hi = mid; }
            starts[b] = base + lo;
        }
    }
    // weight repack: fp32 [o][c] -> bf16 MFMA-fragment order
    if (t < total_groups) {
        int seg = 0, off = t;
        while (seg < 5 && off >= ra.groups[seg]) { off -= ra.groups[seg]; ++seg; }
        int CIN = ra.cin[seg], NK = ra.nk[seg];
        int lane = off & 63;
        int rest = off >> 6;
        int tt = rest % NK;
        int ot = rest / NK;
        int o = ot * 16 + (lane & 15);
        int kk = tt * 32 + (lane >> 4) * 8;
        const float* src = (kk < CIN) ? (ra.Wr[seg] + (size_t)o * CIN + kk)
                                      : (ra.Wn[seg] + (size_t)o * CIN + (kk - CIN));
        floatx4 u0 = *(const floatx4*)src;
        floatx4 u1 = *(const floatx4*)(src + 4);
        short8 d;
        d[0]=f2b(u0[0]); d[1]=f2b(u0[1]); d[2]=f2b(u0[2]); d[3]=f2b(u0[3]);
        d[4]=f2b(u1[0]); d[5]=f2b(u1[1]); d[6]=f2b(u1[2]); d[7]=f2b(u1[3]);
        *(short8*)(ra.dst[seg] + (size_t)off * 8) = d;
    }
}

// ---------------- stride-CSR fill: XCD-aligned dst groups ----------------
__global__ void fill_kernel(const int* __restrict__ g_ei, const int* __restrict__ s_ei,
                            int* __restrict__ dcount, int* __restrict__ csr) {
    int pass = blockIdx.x & (FPASS - 1);
    int lb   = blockIdx.x >> 3;
    int t = lb * blockDim.x + threadIdx.x;
    if (t >= ET) return;
    int dst;
    if (t < E_G) dst = g_ei[E_G + t];
    else         dst = s_ei[E_S + (t - E_G)] + N_G;
    int lo = pass * (NT / FPASS);
    int hi = lo + (NT / FPASS);
    if (dst < lo || dst >= hi) return;
    int src;
    if (t < E_G) src = g_ei[t];
    else         src = s_ei[t - E_G] + N_G;
    int slot = atomicAdd(&dcount[dst], 1);
    if (slot < STRIDE) csr[(size_t)dst * STRIDE + slot] = src;
}

// ---------------- fused layer: gather (fp8->LDS bf16) + dual-GEMM + ELU (+pool) ----
// Block = 64 rows. Phase 1: contiguous-row fp8 gather, sum -> bf16 LDS A1 tile
// (+ bf16 A2 root tile when CIN<=128). Phase 2: 4 waves x 16-row MFMA tiles,
// A-frags from LDS (padded, <=2-way banks), B-frags streamed from L2.
template<int CIN, int COUT, bool POOL>
__global__ __launch_bounds__(256) void fused_layer_kernel(
        const unsigned char* __restrict__ x8, const short* __restrict__ hprev,
        const int* __restrict__ dcount, const int* __restrict__ csr,
        const short* __restrict__ gWF, const short* __restrict__ sWF,
        const float* __restrict__ gB, const float* __restrict__ sB,
        short* __restrict__ out, unsigned char* __restrict__ out8,
        float* __restrict__ pooled, const int* __restrict__ starts) {
    constexpr int NK   = CIN / 16;      // frags over combined K = 2*CIN
    constexpr int NOT  = COUT / 16;
    constexpr bool STA2 = (CIN <= 128); // also stage A2 (root) in LDS
    constexpr int WP   = STA2 ? (2 * CIN + 8) : (CIN + 8);  // +8 shorts: bank-pad
    __shared__ short lds[64 * WP];
    int rowBase = blockIdx.x * 64;
    int tid = threadIdx.x;
    // ---- phase 1: gather-sum fp8 neighbor rows ----
    constexpr int CH = CIN / 16;        // 16-byte fp8 chunks per row
    for (int item = tid; item < 64 * CH; item += 256) {
        int row = item / CH, ch = item % CH;
        int grow = rowBase + row;
        if (grow >= NT) continue;
        int e0 = grow * STRIDE;
        int e1 = e0 + min(dcount[grow], STRIDE);
        float acc[16];
        #pragma unroll
        for (int j = 0; j < 16; ++j) acc[j] = 0.f;
        for (int e = e0; e < e1; ++e) {
            int s = csr[e];
            intx4 w = *(const intx4*)(x8 + (size_t)s * CIN + ch * 16);
            #pragma unroll
            for (int q = 0; q < 4; ++q) {
                floatx2 f0 = __builtin_amdgcn_cvt_pk_f32_fp8(w[q], false);
                floatx2 f1 = __builtin_amdgcn_cvt_pk_f32_fp8(w[q], true);
                acc[q * 4 + 0] += f0[0];
                acc[q * 4 + 1] += f0[1];
                acc[q * 4 + 2] += f1[0];
                acc[q * 4 + 3] += f1[1];
            }
        }
        short8 o0, o1;
        #pragma unroll
        for (int j = 0; j < 8; ++j) { o0[j] = f2b(acc[j]); o1[j] = f2b(acc[8 + j]); }
        short* p = lds + row * WP + ch * 16;
        *(short8*)p = o0;
        *(short8*)(p + 8) = o1;
    }
    if (STA2) {
        constexpr int CH2 = CIN / 8;    // 8-elem bf16 chunks per row
        for (int item = tid; item < 64 * CH2; item += 256) {
            int row = item / CH2, ch = item % CH2;
            int grow = rowBase + row;
            if (grow >= NT) continue;
            *(short8*)(lds + row * WP + CIN + ch * 8) =
                *(const short8*)(hprev + (size_t)grow * CIN + ch * 8);
        }
    }
    __syncthreads();
    // ---- phase 2: MFMA ----
    int wv = tid >> 6, lane = tid & 63;
    int r0 = rowBase + wv * 16;
    if (r0 >= NT) return;
    bool sub = (r0 >= N_G);             // wave-uniform (50000 % 16 == 0)
    const short* WF = sub ? sWF : gWF;
    const float* bias = sub ? sB : gB;
    int id = lane & 15, quad = lane >> 4;
    int lrow = wv * 16 + id;            // row within the block's 64-row LDS tile
    short8 a[NK];
    #pragma unroll
    for (int t = 0; t < NK; ++t) {
        int kk = t * 32 + quad * 8;
        if (STA2 || kk < CIN)
            a[t] = *(const short8*)(lds + lrow * WP + kk);
        else
            a[t] = *(const short8*)(hprev + (size_t)(r0 + id) * CIN + (kk - CIN));
    }
    int seg0 = 0, seg1 = 0;
    if (POOL) {
        while (seg0 < 15 && starts[seg0 + 1] <= r0) ++seg0;
        seg1 = seg0;
        while (seg1 < 15 && starts[seg1 + 1] <= r0 + 15) ++seg1;
    }
    for (int ot = 0; ot < NOT; ++ot) {
        floatx4 acc = {0.f, 0.f, 0.f, 0.f};
        const short* wp = WF + (((size_t)ot * NK) * 64 + lane) * 8;
        #pragma unroll
        for (int t = 0; t < NK; ++t) {
            short8 b = *(const short8*)(wp + (size_t)t * 64 * 8);  // coalesced 1KB/wave
            acc = __builtin_amdgcn_mfma_f32_16x16x32_bf16(a[t], b, acc, 0, 0, 0);
        }
        int o = ot * 16 + id;
        float bv = bias[o];
        float vr[4];
        #pragma unroll
        for (int r = 0; r < 4; ++r) {
            float v = acc[r] + bv;
            vr[r] = (v > 0.f) ? v : (expf(v) - 1.f);
        }
        if (!POOL) {
            #pragma unroll
            for (int r = 0; r < 4; ++r) {
                int nrow = r0 + quad * 4 + r;   // C/D: col=lane&15, row=quad*4+reg
                out[(size_t)nrow * COUT + o] = f2b(vr[r]);
                int w8 = __builtin_amdgcn_cvt_pk_fp8_f32(vr[r], vr[r], 0, false);
                out8[(size_t)nrow * COUT + o] = (unsigned char)(w8 & 0xFF);
            }
        } else if (seg0 == seg1) {
            float vsum = vr[0] + vr[1] + vr[2] + vr[3];
            vsum += __shfl_down(vsum, 32, 64);
            vsum += __shfl_down(vsum, 16, 64);
            if (lane < 16) atomicAdd(&pooled[seg0 * 192 + o], vsum);
        } else {
            #pragma unroll
            for (int r = 0; r < 4; ++r) {
                int nrow = r0 + quad * 4 + r;
                int sg = seg0;
                while (sg < seg1 && starts[sg + 1] <= nrow) ++sg;
                atomicAdd(&pooled[sg * 192 + o], vr[r]);
            }
        }
    }
}

// ---------------- build MLP input [8,448] ----------------
__global__ void build_in_kernel(const float* __restrict__ pooled, const int* __restrict__ starts,
                                const float* __restrict__ point, float* __restrict__ mlp_in) {
    int t = blockIdx.x * blockDim.x + threadIdx.x;
    if (t >= BATCH * 448) return;
    int b = t / 448, j = t % 448;
    float v;
    if (j < 192) {
        int c = starts[b + 1] - starts[b];
        v = pooled[b * 192 + j] / (float)max(c, 1);
    } else if (j < 384) {
        int c = starts[9 + b] - starts[8 + b];
        v = pooled[(8 + b) * 192 + (j - 192)] / (float)max(c, 1);
    } else {
        v = point[b * 64 + (j - 384)];
    }
    mlp_in[t] = v;
}

// ---------------- dense layer: one wave per output neuron ----------------
__global__ __launch_bounds__(256) void dense_wave_kernel(
        const float* __restrict__ in, const float* __restrict__ W,
        const float* __restrict__ bias, float* __restrict__ out,
        int I, int O, int relu) {
    int wave = (blockIdx.x * blockDim.x + threadIdx.x) >> 6;
    int lane = threadIdx.x & 63;
    if (wave >= BATCH * O) return;
    int b = wave / O, o = wave % O;
    const float* x = in + (size_t)b * I;
    const float* w = W + (size_t)o * I;
    float acc = 0.f;
    for (int i = lane; i < I; i += 64) acc += x[i] * w[i];
    #pragma unroll
    for (int off = 32; off > 0; off >>= 1) acc += __shfl_down(acc, off, 64);
    if (lane == 0) {
        acc += bias[o];
        if (relu) acc = fmaxf(acc, 0.f);
        out[wave] = acc;
    }
}

extern "C" void kernel_launch(void* const* d_in, const int* in_sizes, int n_in,
                              void* d_out, int out_size, void* d_ws, size_t ws_size,
                              hipStream_t stream) {
    const float* graph_x = (const float*)d_in[0];
    const float* sub_x   = (const float*)d_in[1];
    const float* point   = (const float*)d_in[2];
    const int*   g_ei    = (const int*)d_in[3];
    const int*   g_batch = (const int*)d_in[4];
    const int*   s_ei    = (const int*)d_in[5];
    const int*   s_batch = (const int*)d_in[6];
    const float* gB1=(const float*)d_in[9],  *gB2=(const float*)d_in[12], *gB3=(const float*)d_in[15];
    const float* sB1=(const float*)d_in[18], *sB2=(const float*)d_in[21], *sB3=(const float*)d_in[24];
    const float* l1W=(const float*)d_in[25], *l1b=(const float*)d_in[26];
    const float* l2W=(const float*)d_in[27], *l2b=(const float*)d_in[28];
    const float* l3W=(const float*)d_in[29], *l3b=(const float*)d_in[30];

    char* ws = (char*)d_ws;
    size_t off = 0;
    auto alloc = [&](size_t bytes) -> char* {
        char* p = ws + off;
        off = (off + bytes + 255) & ~(size_t)255;
        return p;
    };
    int* dcount = (int*)alloc((size_t)NT * 4);
    int* csr = (int*)alloc((size_t)NT * STRIDE * 4);   // 15.36 MB stride-CSR

    // fragment-ordered bf16 weight slab: per layer COUT*2*CIN elems
    const int fsz[3] = {128 * 2 * 64, 256 * 2 * 128, 192 * 2 * 256};
    short* wfrag = (short*)alloc((size_t)(fsz[0] + fsz[1] + fsz[2]) * 2 * 2);
    short* gWF[3], *sWF[3];
    { size_t o2 = 0;
      for (int l = 0; l < 3; ++l) { gWF[l] = wfrag + o2; o2 += fsz[l]; }
      for (int l = 0; l < 3; ++l) { sWF[l] = wfrag + o2; o2 += fsz[l]; } }

    short* X0  = (short*)alloc((size_t)NT * 64 * 2);
    unsigned char* X0_8 = (unsigned char*)alloc((size_t)NT * 64);
    short* h1  = (short*)alloc((size_t)NT * 128 * 2);
    short* h2  = (short*)alloc((size_t)NT * 256 * 2);
    unsigned char* h1_8 = (unsigned char*)alloc((size_t)NT * 128);
    unsigned char* h2_8 = (unsigned char*)alloc((size_t)NT * 256);

    float* pooled = (float*)alloc(16 * 192 * 4);
    int* starts = (int*)alloc(17 * 4);
    float* mlp_in = (float*)alloc(BATCH * 448 * 4);
    float* mlp_h1 = (float*)alloc(BATCH * 600 * 4);
    float* mlp_h2 = (float*)alloc(BATCH * 256 * 4);

    // weight repack args (merged into init)
    RepArgs ra;
    const int cin_l[3] = {64, 128, 256};
    const int nk_l[3]  = {4, 8, 16};
    const int not_l[3] = {8, 16, 12};
    const int wr_idx[6] = {7, 10, 13, 16, 19, 22};
    int total_groups = 0;
    for (int s = 0; s < 6; ++s) {
        int l = s % 3;
        ra.Wr[s] = (const float*)d_in[wr_idx[s]];
        ra.Wn[s] = (const float*)d_in[wr_idx[s] + 1];
        ra.dst[s] = (s < 3) ? gWF[l] : sWF[l];
        ra.cin[s] = cin_l[l];
        ra.nk[s] = nk_l[l];
        ra.groups[s] = not_l[l] * nk_l[l] * 64;
        total_groups += ra.groups[s];
    }

    init_kernel<<<(NT * 16 + 255) / 256, 256, 0, stream>>>(graph_x, sub_x, X0, X0_8, dcount,
                                                           pooled, g_batch, s_batch, starts,
                                                           ra, total_groups);

    fill_kernel<<<((ET + 255) / 256) * FPASS, 256, 0, stream>>>(g_ei, s_ei, dcount, csr);

    const int gx = (NT + 63) / 64;   // 938 blocks, 64 rows each

    fused_layer_kernel<64, 128, false><<<gx, 256, 0, stream>>>(
        X0_8, X0, dcount, csr, gWF[0], sWF[0], gB1, sB1, h1, h1_8, nullptr, nullptr);
    fused_layer_kernel<128, 256, false><<<gx, 256, 0, stream>>>(
        h1_8, h1, dcount, csr, gWF[1], sWF[1], gB2, sB2, h2, h2_8, nullptr, nullptr);
    fused_layer_kernel<256, 192, true><<<gx, 256, 0, stream>>>(
        h2_8, h2, dcount, csr, gWF[2], sWF[2], gB3, sB3, nullptr, nullptr, pooled, starts);

    build_in_kernel<<<(BATCH * 448 + 255) / 256, 256, 0, stream>>>(pooled, starts, point, mlp_in);
    dense_wave_kernel<<<(BATCH * 600 + 3) / 4, 256, 0, stream>>>(mlp_in, l1W, l1b, mlp_h1, 448, 600, 1);
    dense_wave_kernel<<<(BATCH * 256 + 3) / 4, 256, 0, stream>>>(mlp_h1, l2W, l2b, mlp_h2, 600, 256, 1);
    dense_wave_kernel<<<(BATCH * 64 + 3) / 4, 256, 0, stream>>>(mlp_h2, l3W, l3b, (float*)d_out, 256, 64, 0);
}

// Round 18
// 383.063 us; speedup vs baseline: 1.0714x; 1.0321x over previous
//
#include <hip/hip_runtime.h>
#include <cmath>

typedef __attribute__((ext_vector_type(8))) short short8;
typedef __attribute__((ext_vector_type(4))) short shortx4;
typedef __attribute__((ext_vector_type(4))) float floatx4;
typedef __attribute__((ext_vector_type(2))) float floatx2;
typedef __attribute__((ext_vector_type(4))) int intx4;
typedef __attribute__((ext_vector_type(2))) int intx2;

#define N_G 50000
#define E_G 800000
#define N_S 10000
#define E_S 160000
#define NT (N_G + N_S)      // 60000 combined nodes
#define ET (E_G + E_S)      // 960000 combined edges
#define BATCH 8
#define STRIDE 64           // fixed CSR stride (deg ~ Poisson(16); P(>64) ~ 1e-18)
#define FPASS 8             // fill: XCD-aligned dst groups

__device__ __forceinline__ float b2f(short s) {
    unsigned u = ((unsigned)(unsigned short)s) << 16;
    return __builtin_bit_cast(float, u);
}
__device__ __forceinline__ short f2b(float f) {
    unsigned u = __builtin_bit_cast(unsigned, f);
    u += 0x7FFF + ((u >> 16) & 1);   // RNE
    return (short)(u >> 16);
}
// 8 fp8 bytes -> 8 bf16 (in-register root-path dequant)
__device__ __forceinline__ short8 fp8x8_to_bf16(intx2 w) {
    floatx2 f0 = __builtin_amdgcn_cvt_pk_f32_fp8(w[0], false);
    floatx2 f1 = __builtin_amdgcn_cvt_pk_f32_fp8(w[0], true);
    floatx2 f2 = __builtin_amdgcn_cvt_pk_f32_fp8(w[1], false);
    floatx2 f3 = __builtin_amdgcn_cvt_pk_f32_fp8(w[1], true);
    short8 r;
    r[0]=f2b(f0[0]); r[1]=f2b(f0[1]); r[2]=f2b(f1[0]); r[3]=f2b(f1[1]);
    r[4]=f2b(f2[0]); r[5]=f2b(f2[1]); r[6]=f2b(f3[0]); r[7]=f2b(f3[1]);
    return r;
}

// ---------------- init: zeros + bounds + X0 fp8 + weight repack (merged) ------
struct RepArgs { const float* Wr[6]; const float* Wn[6]; short* dst[6]; int cin[6]; int nk[6]; int groups[6]; };
__global__ void init_kernel(const float* __restrict__ gx, const float* __restrict__ sx,
                            unsigned char* __restrict__ X0_8,
                            int* __restrict__ dcount, float* __restrict__ pooled,
                            const int* __restrict__ g_batch, const int* __restrict__ s_batch,
                            int* __restrict__ starts, RepArgs ra, int total_groups) {
    int t = blockIdx.x * blockDim.x + threadIdx.x;
    if (t < NT * 16) {
        size_t e = (size_t)t * 4;
        const float* src = (e < (size_t)N_G * 64) ? (gx + e) : (sx + (e - (size_t)N_G * 64));
        floatx4 v = *(const floatx4*)src;
        int w8 = 0;
        w8 = __builtin_amdgcn_cvt_pk_fp8_f32(v[0], v[1], w8, false);
        w8 = __builtin_amdgcn_cvt_pk_fp8_f32(v[2], v[3], w8, true);
        *(unsigned int*)(X0_8 + e) = (unsigned int)w8;
    }
    if (t < NT) dcount[t] = 0;
    if (t < 16 * 192) pooled[t] = 0.f;
    if (t <= 16) {
        int b = t;
        if (b == 16) { starts[16] = NT; }
        else {
            int key, n, base;
            const int* arr;
            if (b < 8) { arr = g_batch; n = N_G; key = b; base = 0; }
            else       { arr = s_batch; n = N_S; key = b - 8; base = N_G; }
            int lo = 0, hi = n;
            while (lo < hi) { int mid = (lo + hi) >> 1; if (arr[mid] < key) lo = mid + 1; else hi = mid; }
            starts[b] = base + lo;
        }
    }
    // weight repack: fp32 [o][c] -> bf16 MFMA-fragment order
    if (t < total_groups) {
        int seg = 0, off = t;
        while (seg < 5 && off >= ra.groups[seg]) { off -= ra.groups[seg]; ++seg; }
        int CIN = ra.cin[seg], NK = ra.nk[seg];
        int lane = off & 63;
        int rest = off >> 6;
        int tt = rest % NK;
        int ot = rest / NK;
        int o = ot * 16 + (lane & 15);
        int kk = tt * 32 + (lane >> 4) * 8;
        const float* src = (kk < CIN) ? (ra.Wr[seg] + (size_t)o * CIN + kk)
                                      : (ra.Wn[seg] + (size_t)o * CIN + (kk - CIN));
        floatx4 u0 = *(const floatx4*)src;
        floatx4 u1 = *(const floatx4*)(src + 4);
        short8 d;
        d[0]=f2b(u0[0]); d[1]=f2b(u0[1]); d[2]=f2b(u0[2]); d[3]=f2b(u0[3]);
        d[4]=f2b(u1[0]); d[5]=f2b(u1[1]); d[6]=f2b(u1[2]); d[7]=f2b(u1[3]);
        *(short8*)(ra.dst[seg] + (size_t)off * 8) = d;
    }
}

// ---------------- stride-CSR fill: XCD-aligned dst groups ----------------
__global__ void fill_kernel(const int* __restrict__ g_ei, const int* __restrict__ s_ei,
                            int* __restrict__ dcount, int* __restrict__ csr) {
    int pass = blockIdx.x & (FPASS - 1);
    int lb   = blockIdx.x >> 3;
    int t = lb * blockDim.x + threadIdx.x;
    if (t >= ET) return;
    int dst;
    if (t < E_G) dst = g_ei[E_G + t];
    else         dst = s_ei[E_S + (t - E_G)] + N_G;
    int lo = pass * (NT / FPASS);
    int hi = lo + (NT / FPASS);
    if (dst < lo || dst >= hi) return;
    int src;
    if (t < E_G) src = g_ei[t];
    else         src = s_ei[t - E_G] + N_G;
    int slot = atomicAdd(&dcount[dst], 1);
    if (slot < STRIDE) csr[(size_t)dst * STRIDE + slot] = src;
}

// ---------------- fp8 gather aggregation (all layers); bf16 out -------------
template<int C>
__global__ void agg8_kernel(const unsigned char* __restrict__ x8, const int* __restrict__ dcount,
                            const int* __restrict__ csr, short* __restrict__ out) {
    constexpr int C16 = C / 16;
    int t = blockIdx.x * blockDim.x + threadIdx.x;
    if (t >= NT * C16) return;
    int node = t / C16;
    int ch   = t % C16;
    int e0 = node * STRIDE;
    int e1 = e0 + min(dcount[node], STRIDE);
    float acc[16];
    #pragma unroll
    for (int j = 0; j < 16; ++j) acc[j] = 0.f;
    for (int e = e0; e < e1; ++e) {
        int s = csr[e];
        intx4 w = *(const intx4*)(x8 + (size_t)s * C + ch * 16);
        #pragma unroll
        for (int q = 0; q < 4; ++q) {
            floatx2 f0 = __builtin_amdgcn_cvt_pk_f32_fp8(w[q], false);
            floatx2 f1 = __builtin_amdgcn_cvt_pk_f32_fp8(w[q], true);
            acc[q * 4 + 0] += f0[0];
            acc[q * 4 + 1] += f0[1];
            acc[q * 4 + 2] += f1[0];
            acc[q * 4 + 3] += f1[1];
        }
    }
    short8 o0, o1;
    #pragma unroll
    for (int j = 0; j < 8; ++j) { o0[j] = f2b(acc[j]); o1[j] = f2b(acc[8 + j]); }
    short8* q = (short8*)(out + (size_t)node * C + ch * 16);
    q[0] = o0; q[1] = o1;
}

// ---------------- dual-GEMM + bias + ELU; A1=bf16 agg, A2=fp8 root ----------
// Stores fp8 only (next layer's gather + root payload). POOL: pooled atomics.
template<int CIN, int COUT, bool POOL>
__global__ __launch_bounds__(256) void gemm_elu_kernel(
        const short* __restrict__ A1, const unsigned char* __restrict__ A2_8,
        const short* __restrict__ gWF, const short* __restrict__ sWF,
        const float* __restrict__ gB, const float* __restrict__ sB,
        unsigned char* __restrict__ out8,
        float* __restrict__ pooled, const int* __restrict__ starts) {
    constexpr int NK  = CIN / 16;
    constexpr int NOT = COUT / 16;
    int wave = (blockIdx.x * blockDim.x + threadIdx.x) >> 6;
    int lane = threadIdx.x & 63;
    int r0 = wave * 16;
    if (r0 >= NT) return;
    bool sub = (r0 >= N_G);          // wave-uniform (50000 % 16 == 0)
    const short* WF = sub ? sWF : gWF;
    const float* bias = sub ? sB : gB;
    int id = lane & 15, quad = lane >> 4;
    int arow = r0 + id;              // A: m=lane&15, k=quad*8+j
    short8 a[NK];
    #pragma unroll
    for (int t = 0; t < NK; ++t) {
        int kk = t * 32 + quad * 8;
        if (kk < CIN) {
            a[t] = *(const short8*)(A1 + (size_t)arow * CIN + kk);
        } else {
            intx2 w = *(const intx2*)(A2_8 + (size_t)arow * CIN + (kk - CIN));
            a[t] = fp8x8_to_bf16(w);
        }
    }
    int seg0 = 0, seg1 = 0;
    if (POOL) {
        while (seg0 < 15 && starts[seg0 + 1] <= r0) ++seg0;
        seg1 = seg0;
        while (seg1 < 15 && starts[seg1 + 1] <= r0 + 15) ++seg1;
    }
    for (int ot = 0; ot < NOT; ++ot) {
        floatx4 acc = {0.f, 0.f, 0.f, 0.f};
        const short* wp = WF + (((size_t)ot * NK) * 64 + lane) * 8;
        #pragma unroll
        for (int t = 0; t < NK; ++t) {
            short8 b = *(const short8*)(wp + (size_t)t * 64 * 8);  // coalesced 1KB/wave
            acc = __builtin_amdgcn_mfma_f32_16x16x32_bf16(a[t], b, acc, 0, 0, 0);
        }
        int o = ot * 16 + id;
        float bv = bias[o];
        float vr[4];
        #pragma unroll
        for (int r = 0; r < 4; ++r) {
            float v = acc[r] + bv;
            vr[r] = (v > 0.f) ? v : (expf(v) - 1.f);
        }
        if (!POOL) {
            #pragma unroll
            for (int r = 0; r < 4; ++r) {
                int nrow = r0 + quad * 4 + r;   // C/D: col=lane&15, row=quad*4+reg
                int w8 = __builtin_amdgcn_cvt_pk_fp8_f32(vr[r], vr[r], 0, false);
                out8[(size_t)nrow * COUT + o] = (unsigned char)(w8 & 0xFF);
            }
        } else if (seg0 == seg1) {
            float vsum = vr[0] + vr[1] + vr[2] + vr[3];
            vsum += __shfl_down(vsum, 32, 64);
            vsum += __shfl_down(vsum, 16, 64);
            if (lane < 16) atomicAdd(&pooled[seg0 * 192 + o], vsum);
        } else {
            #pragma unroll
            for (int r = 0; r < 4; ++r) {
                int nrow = r0 + quad * 4 + r;
                int sg = seg0;
                while (sg < seg1 && starts[sg + 1] <= nrow) ++sg;
                atomicAdd(&pooled[sg * 192 + o], vr[r]);
            }
        }
    }
}

// ---------------- MLP layer 1: one wave per (b,o); builds x on the fly ----------
__global__ __launch_bounds__(256) void mlp1_kernel(
        const float* __restrict__ pooled, const int* __restrict__ starts,
        const float* __restrict__ point, const float* __restrict__ W,
        const float* __restrict__ bias, float* __restrict__ out) {
    int wave = (blockIdx.x * blockDim.x + threadIdx.x) >> 6;
    int lane = threadIdx.x & 63;
    if (wave >= BATCH * 600) return;
    int b = wave / 600, o = wave % 600;
    float invg = 1.f / (float)max(starts[b + 1] - starts[b], 1);
    float invs = 1.f / (float)max(starts[9 + b] - starts[8 + b], 1);
    const float* w = W + (size_t)o * 448;
    float acc = 0.f;
    for (int i = lane; i < 448; i += 64) {
        float x;
        if (i < 192)      x = pooled[b * 192 + i] * invg;
        else if (i < 384) x = pooled[(8 + b) * 192 + (i - 192)] * invs;
        else              x = point[b * 64 + (i - 384)];
        acc += x * w[i];
    }
    #pragma unroll
    for (int off = 32; off > 0; off >>= 1) acc += __shfl_down(acc, off, 64);
    if (lane == 0) out[wave] = fmaxf(acc + bias[o], 0.f);
}

// ---------------- dense layer: one wave per output neuron ----------------
__global__ __launch_bounds__(256) void dense_wave_kernel(
        const float* __restrict__ in, const float* __restrict__ W,
        const float* __restrict__ bias, float* __restrict__ out,
        int I, int O, int relu) {
    int wave = (blockIdx.x * blockDim.x + threadIdx.x) >> 6;
    int lane = threadIdx.x & 63;
    if (wave >= BATCH * O) return;
    int b = wave / O, o = wave % O;
    const float* x = in + (size_t)b * I;
    const float* w = W + (size_t)o * I;
    float acc = 0.f;
    for (int i = lane; i < I; i += 64) acc += x[i] * w[i];
    #pragma unroll
    for (int off = 32; off > 0; off >>= 1) acc += __shfl_down(acc, off, 64);
    if (lane == 0) {
        acc += bias[o];
        if (relu) acc = fmaxf(acc, 0.f);
        out[wave] = acc;
    }
}

extern "C" void kernel_launch(void* const* d_in, const int* in_sizes, int n_in,
                              void* d_out, int out_size, void* d_ws, size_t ws_size,
                              hipStream_t stream) {
    const float* graph_x = (const float*)d_in[0];
    const float* sub_x   = (const float*)d_in[1];
    const float* point   = (const float*)d_in[2];
    const int*   g_ei    = (const int*)d_in[3];
    const int*   g_batch = (const int*)d_in[4];
    const int*   s_ei    = (const int*)d_in[5];
    const int*   s_batch = (const int*)d_in[6];
    const float* gB1=(const float*)d_in[9],  *gB2=(const float*)d_in[12], *gB3=(const float*)d_in[15];
    const float* sB1=(const float*)d_in[18], *sB2=(const float*)d_in[21], *sB3=(const float*)d_in[24];
    const float* l1W=(const float*)d_in[25], *l1b=(const float*)d_in[26];
    const float* l2W=(const float*)d_in[27], *l2b=(const float*)d_in[28];
    const float* l3W=(const float*)d_in[29], *l3b=(const float*)d_in[30];

    char* ws = (char*)d_ws;
    size_t off = 0;
    auto alloc = [&](size_t bytes) -> char* {
        char* p = ws + off;
        off = (off + bytes + 255) & ~(size_t)255;
        return p;
    };
    int* dcount = (int*)alloc((size_t)NT * 4);
    int* csr = (int*)alloc((size_t)NT * STRIDE * 4);   // 15.36 MB stride-CSR

    // fragment-ordered bf16 weight slab: per layer COUT*2*CIN elems
    const int fsz[3] = {128 * 2 * 64, 256 * 2 * 128, 192 * 2 * 256};
    short* wfrag = (short*)alloc((size_t)(fsz[0] + fsz[1] + fsz[2]) * 2 * 2);
    short* gWF[3], *sWF[3];
    { size_t o2 = 0;
      for (int l = 0; l < 3; ++l) { gWF[l] = wfrag + o2; o2 += fsz[l]; }
      for (int l = 0; l < 3; ++l) { sWF[l] = wfrag + o2; o2 += fsz[l]; } }

    unsigned char* X0_8 = (unsigned char*)alloc((size_t)NT * 64);
    short* agg = (short*)alloc((size_t)NT * 256 * 2);
    unsigned char* h1_8 = (unsigned char*)alloc((size_t)NT * 128);
    unsigned char* h2_8 = (unsigned char*)alloc((size_t)NT * 256);

    float* pooled = (float*)alloc(16 * 192 * 4);
    int* starts = (int*)alloc(17 * 4);
    float* mlp_h1 = (float*)alloc(BATCH * 600 * 4);
    float* mlp_h2 = (float*)alloc(BATCH * 256 * 4);

    // weight repack args (merged into init)
    RepArgs ra;
    const int cin_l[3] = {64, 128, 256};
    const int nk_l[3]  = {4, 8, 16};
    const int not_l[3] = {8, 16, 12};
    const int wr_idx[6] = {7, 10, 13, 16, 19, 22};
    int total_groups = 0;
    for (int s = 0; s < 6; ++s) {
        int l = s % 3;
        ra.Wr[s] = (const float*)d_in[wr_idx[s]];
        ra.Wn[s] = (const float*)d_in[wr_idx[s] + 1];
        ra.dst[s] = (s < 3) ? gWF[l] : sWF[l];
        ra.cin[s] = cin_l[l];
        ra.nk[s] = nk_l[l];
        ra.groups[s] = not_l[l] * nk_l[l] * 64;
        total_groups += ra.groups[s];
    }

    init_kernel<<<(NT * 16 + 255) / 256, 256, 0, stream>>>(graph_x, sub_x, X0_8, dcount,
                                                           pooled, g_batch, s_batch, starts,
                                                           ra, total_groups);

    fill_kernel<<<((ET + 255) / 256) * FPASS, 256, 0, stream>>>(g_ei, s_ei, dcount, csr);

    constexpr int NW = NT / 16;
    const int gemm_blocks = (NW + 3) / 4;

    agg8_kernel<64><<<(NT * 4 + 255) / 256, 256, 0, stream>>>(X0_8, dcount, csr, agg);
    gemm_elu_kernel<64, 128, false><<<gemm_blocks, 256, 0, stream>>>(
        agg, X0_8, gWF[0], sWF[0], gB1, sB1, h1_8, nullptr, nullptr);
    agg8_kernel<128><<<(NT * 8 + 255) / 256, 256, 0, stream>>>(h1_8, dcount, csr, agg);
    gemm_elu_kernel<128, 256, false><<<gemm_blocks, 256, 0, stream>>>(
        agg, h1_8, gWF[1], sWF[1], gB2, sB2, h2_8, nullptr, nullptr);
    agg8_kernel<256><<<(NT * 16 + 255) / 256, 256, 0, stream>>>(h2_8, dcount, csr, agg);
    gemm_elu_kernel<256, 192, true><<<gemm_blocks, 256, 0, stream>>>(
        agg, h2_8, gWF[2], sWF[2], gB3, sB3, nullptr, pooled, starts);

    mlp1_kernel<<<(BATCH * 600 + 3) / 4, 256, 0, stream>>>(pooled, starts, point, l1W, l1b, mlp_h1);
    dense_wave_kernel<<<(BATCH * 256 + 3) / 4, 256, 0, stream>>>(mlp_h1, l2W, l2b, mlp_h2, 600, 256, 1);
    dense_wave_kernel<<<(BATCH * 64 + 3) / 4, 256, 0, stream>>>(mlp_h2, l3W, l3b, (float*)d_out, 256, 64, 0);
}